// Round 16
// baseline (397.181 us; speedup 1.0000x reference)
//
#include <hip/hip_runtime.h>
#include <hip/hip_bf16.h>

typedef __attribute__((ext_vector_type(8))) short short8;
typedef __attribute__((ext_vector_type(4))) float floatx4;

#define NSEQ 16
#define SEQ 128
#define DIM 256
#define HID 256
#define K3H 768
#define K2D 512
#define LOG2E 1.442695041f
#define LOG2E2 2.885390082f
#define WS_STRIDE 772

__device__ __forceinline__ float frcp(float x) { return __builtin_amdgcn_rcpf(x); }
__device__ __forceinline__ unsigned short bf16bits(float v) {
    unsigned u = __builtin_bit_cast(unsigned, v);
    unsigned r = (u + 0x7FFFu + ((u >> 16) & 1u)) >> 16;
    return (unsigned short)r;
}
__device__ __forceinline__ void load_lds16(const float* gsrc, float* ldsbase) {
    __builtin_amdgcn_global_load_lds(
        (const __attribute__((address_space(1))) void*)gsrc,
        (__attribute__((address_space(3))) void*)ldsbase, 16, 0, 0);
}

// Fused pipeline. Roles by blockIdx.x:
//   0..15    GRU consumer (1 seq each; spins on f3 tile flags)
//   16..143  k1: left/right = x@{w1,w2}*2log2e        -> f1[seq]   (target 8)
//   144..399 k2: scores/softmax/context               -> f2[seq*2+half] (target 8)
//   400..527 k3: xp = [x|c]@gk + bias, prescaled MFMA -> f3[mtile] (target 4)
// Producer signal: all-thread threadfence -> syncthreads -> tid0 atomicAdd.
// Consumer wait: tid0 polls atomicAdd(f,0) -> syncthreads -> all-thread threadfence
// (RMW poll reads coherence point; fence invalidates stale per-XCD L2 on replays).
__global__ __launch_bounds__(512) void k_fused(
        const float* __restrict__ x, const float* __restrict__ w1,
        const float* __restrict__ w2, const float* __restrict__ bias,
        const float* __restrict__ v3, const float* __restrict__ gk,
        const float* __restrict__ rec, const float* __restrict__ gb,
        float* __restrict__ left, float* __restrict__ right,
        float* __restrict__ cbuf, float* __restrict__ xp,
        float* __restrict__ out, unsigned* __restrict__ flags) {
    __shared__ __align__(16) char smem[59648];
    unsigned* f1 = flags;         // 16
    unsigned* f2 = flags + 16;    // 32
    unsigned* f3 = flags + 48;    // 32
    const int bid = blockIdx.x;
    const int tid = threadIdx.x;

    if (bid < 16) {
        // ================= GRU consumer =================
        float* ws = (float*)smem;                                   // 49408B
        float* xqa = (float*)(smem + 49408);
        float* xqb = (float*)(smem + 52480);
        float* xqc = (float*)(smem + 55552);
        unsigned short (*hbf)[HID] = (unsigned short(*)[HID])(smem + 58624);
        const int lane = tid & 63;
        const int wv   = tid >> 6;
        const int seq  = bid;
        const int l15  = lane & 15;
        const int g4   = lane >> 4;

        // weight preload first: depends only on rec; overlaps producer chain
        short8 Bf[6][8];
        #pragma unroll
        for (int part = 0; part < 16; ++part) {
            #pragma unroll
            for (int q = 0; q < 6; ++q) {
                int fi = q * 512 + tid;
                int row = fi / 192, c4 = fi % 192;
                reinterpret_cast<float4*>(ws)[row * (WS_STRIDE / 4) + c4] =
                    reinterpret_cast<const float4*>(rec + part * 16 * K3H)[fi];
            }
            __syncthreads();
            const int kc = part >> 1, half = part & 1;
            #pragma unroll
            for (int u = 0; u < 6; ++u) {
                const float sc = (u >= 4) ? LOG2E2 : LOG2E;
                const int col = (u >> 1) * 256 + (u & 1) * 16 + wv * 32 + l15;
                #pragma unroll
                for (int j = 0; j < 8; ++j) {
                    int r = g4 * 8 + j;
                    if ((r >> 4) == half)
                        Bf[u][kc][j] = (short)bf16bits(ws[(r & 15) * WS_STRIDE + col] * sc);
                }
            }
            __syncthreads();
        }

        const int dd = wv * 32 + (lane & 31);
        const float brh_l = gb[K3H + 512 + dd] * LOG2E2;
        const int tsel = (lane >> 4) & 1;
        const float* xps = xp + (size_t)seq * SEQ * K3H;
        float* outs = out + (size_t)seq * SEQ * HID;
        float h = 0.f;
        if (tid < HID) hbf[0][tid] = 0;

        // wait for xp tile A (rows 0..63 of this seq)
        if (tid == 0) { while (atomicAdd(&f3[seq * 2], 0u) < 4u) __builtin_amdgcn_s_sleep(2); }
        __syncthreads();
        __threadfence();

        if (wv < 3) {
            load_lds16(xps + wv * 256 + (lane << 2),       xqa + wv * 256);
            load_lds16(xps + K3H + wv * 256 + (lane << 2), xqb + wv * 256);
        }
        asm volatile("s_waitcnt vmcnt(0)" ::: "memory");
        __syncthreads();

        float* p0 = xqa;
        float* p1 = xqb;
        float* p2 = xqc;

        #define K4_STEP(s_, CB, NB)                                                         \
        {                                                                                   \
            const int sp = ((s_) + 2 < SEQ) ? (s_) + 2 : SEQ - 1;                           \
            if (wv < 3)                                                                     \
                load_lds16(xps + (size_t)sp * K3H + wv * 256 + (lane << 2), p2 + wv * 256); \
            short8 av[8];                                                                   \
            _Pragma("unroll")                                                               \
            for (int kc = 0; kc < 8; ++kc)                                                  \
                av[kc] = *reinterpret_cast<const short8*>(&hbf[CB][kc * 32 + g4 * 8]);      \
            const float xz = p0[dd];                                                        \
            const float xr = p0[256 + dd];                                                  \
            const float xh = p0[512 + dd];                                                  \
            floatx4 C[6];                                                                   \
            _Pragma("unroll")                                                               \
            for (int u = 0; u < 6; ++u) C[u] = (floatx4){0.f, 0.f, 0.f, 0.f};               \
            _Pragma("unroll")                                                               \
            for (int kc = 0; kc < 8; ++kc) {                                                \
                _Pragma("unroll")                                                           \
                for (int u = 0; u < 6; ++u)                                                 \
                    C[u] = __builtin_amdgcn_mfma_f32_16x16x32_bf16(av[kc], Bf[u][kc],       \
                                                                   C[u], 0, 0, 0);         \
            }                                                                               \
            if (lane < 32) {                                                                \
                float rz = tsel ? C[1][0] : C[0][0];                                        \
                float rr = tsel ? C[3][0] : C[2][0];                                        \
                float rh = tsel ? C[5][0] : C[4][0];                                        \
                float z  = frcp(1.f + __builtin_amdgcn_exp2f(-(rz + xz)));                  \
                float r  = frcp(1.f + __builtin_amdgcn_exp2f(-(rr + xr)));                  \
                float th = fmaf(r, rh + brh_l, xh);                                         \
                float hh = 1.f - 2.f * frcp(1.f + __builtin_amdgcn_exp2f(th));              \
                h = hh + z * (h - hh);                                                      \
                hbf[NB][dd] = bf16bits(h);                                                  \
                outs[(s_) * HID + dd] = h;                                                  \
            }                                                                               \
            asm volatile("s_waitcnt vmcnt(3) lgkmcnt(0)\n\ts_barrier" ::: "memory");        \
            float* tmp_ = p0; p0 = p1; p1 = p2; p2 = tmp_;                                  \
        }

        for (int s = 0; s < 62; s += 2) {
            K4_STEP(s,     0, 1)
            K4_STEP(s + 1, 1, 0)
        }
        // wait for xp tile B (rows 64..127) before DMAing row 64 at step 62
        if (tid == 0) { while (atomicAdd(&f3[seq * 2 + 1], 0u) < 4u) __builtin_amdgcn_s_sleep(2); }
        __syncthreads();
        __threadfence();   // drains vmcnt (safe: only strengthens counted-wait invariant)
        for (int s = 62; s < SEQ; s += 2) {
            K4_STEP(s,     0, 1)
            K4_STEP(s + 1, 1, 0)
        }
        #undef K4_STEP

    } else if (bid < 144) {
        // ================= k1 producer: 16 rows/block =================
        const int kb = bid - 16;
        const int r0 = kb * 16;
        float (*xs)[DIM] = (float(*)[DIM])smem;
        const int col = tid & 255, hf = tid >> 8;
        #pragma unroll
        for (int i = 0; i < 8; ++i)
            xs[hf * 8 + i][col] = x[(size_t)(r0 + hf * 8 + i) * DIM + col];
        __syncthreads();
        float accL[8], accR[8];
        #pragma unroll
        for (int i = 0; i < 8; ++i) { accL[i] = 0.f; accR[i] = 0.f; }
        #pragma unroll 4
        for (int d = 0; d < DIM; ++d) {
            float wa = w1[d * DIM + col];
            float wb = w2[d * DIM + col];
            #pragma unroll
            for (int i = 0; i < 8; ++i) {
                float xv = xs[hf * 8 + i][d];
                accL[i] = fmaf(xv, wa, accL[i]);
                accR[i] = fmaf(xv, wb, accR[i]);
            }
        }
        #pragma unroll
        for (int i = 0; i < 8; ++i) {
            left[(size_t)(r0 + hf * 8 + i) * DIM + col]  = accL[i] * LOG2E2;
            right[(size_t)(r0 + hf * 8 + i) * DIM + col] = accR[i] * LOG2E2;
        }
        __threadfence();
        __syncthreads();
        if (tid == 0) atomicAdd(&f1[kb >> 3], 1u);

    } else if (bid < 400) {
        // ================= k2 producer: 8 rows/block, wave-per-row =================
        const int kb = bid - 144;
        const int b  = kb >> 4;
        const int m0 = (kb & 15) * 8;
        float (*lm)[DIM] = (float(*)[DIM])smem;
        float* v3s = (float*)(smem + 8192);
        float (*P)[SEQ] = (float(*)[SEQ])(smem + 9216);

        if (tid == 0) { while (atomicAdd(&f1[b], 0u) < 8u) __builtin_amdgcn_s_sleep(2); }
        __syncthreads();
        __threadfence();

        {
            const int col = tid & 255, hf = tid >> 8;
            #pragma unroll
            for (int i = 0; i < 4; ++i)
                lm[hf * 4 + i][col] =
                    left[(size_t)(b * SEQ + m0 + hf * 4 + i) * DIM + col] + bias[col] * LOG2E2;
            if (tid < 256) v3s[tid] = v3[tid];
        }
        __syncthreads();

        const int w  = tid >> 6;
        const int nl = tid & 63;
        float s0 = 0.f, s1 = 0.f;
        const float4* lv4 = reinterpret_cast<const float4*>(lm[w]);
        const float4* vv4 = reinterpret_cast<const float4*>(v3s);
        const float4* r0v = reinterpret_cast<const float4*>(right + (size_t)(b * SEQ + nl) * DIM);
        const float4* r1v = reinterpret_cast<const float4*>(right + (size_t)(b * SEQ + nl + 64) * DIM);
        #pragma unroll 2
        for (int d4 = 0; d4 < DIM / 4; ++d4) {
            float4 lv = lv4[d4];
            float4 vv = vv4[d4];
            float4 ra = r0v[d4];
            float4 rb = r1v[d4];
            float a0 = 1.f - 2.f * frcp(1.f + __builtin_amdgcn_exp2f(lv.x + ra.x));
            float a1 = 1.f - 2.f * frcp(1.f + __builtin_amdgcn_exp2f(lv.y + ra.y));
            float a2 = 1.f - 2.f * frcp(1.f + __builtin_amdgcn_exp2f(lv.z + ra.z));
            float a3 = 1.f - 2.f * frcp(1.f + __builtin_amdgcn_exp2f(lv.w + ra.w));
            s0 = fmaf(a0, vv.x, s0); s0 = fmaf(a1, vv.y, s0);
            s0 = fmaf(a2, vv.z, s0); s0 = fmaf(a3, vv.w, s0);
            float b0 = 1.f - 2.f * frcp(1.f + __builtin_amdgcn_exp2f(lv.x + rb.x));
            float b1 = 1.f - 2.f * frcp(1.f + __builtin_amdgcn_exp2f(lv.y + rb.y));
            float b2 = 1.f - 2.f * frcp(1.f + __builtin_amdgcn_exp2f(lv.z + rb.z));
            float b3 = 1.f - 2.f * frcp(1.f + __builtin_amdgcn_exp2f(lv.w + rb.w));
            s1 = fmaf(b0, vv.x, s1); s1 = fmaf(b1, vv.y, s1);
            s1 = fmaf(b2, vv.z, s1); s1 = fmaf(b3, vv.w, s1);
        }
        float mx = fmaxf(s0, s1);
        #pragma unroll
        for (int off = 32; off >= 1; off >>= 1) mx = fmaxf(mx, __shfl_xor(mx, off, 64));
        float e0 = __expf(s0 - mx), e1 = __expf(s1 - mx);
        float sm = e0 + e1;
        #pragma unroll
        for (int off = 32; off >= 1; off >>= 1) sm += __shfl_xor(sm, off, 64);
        float inv = frcp(sm);
        P[w][nl]      = e0 * inv;
        P[w][nl + 64] = e1 * inv;
        __syncthreads();

        const int d  = tid & 255;
        const int rg = tid >> 8;
        float acc[4] = {0.f, 0.f, 0.f, 0.f};
        const float* xb = x + (size_t)b * SEQ * DIM;
        for (int nc = 0; nc < SEQ / 4; ++nc) {
            float xv0 = xb[(nc * 4 + 0) * DIM + d];
            float xv1 = xb[(nc * 4 + 1) * DIM + d];
            float xv2 = xb[(nc * 4 + 2) * DIM + d];
            float xv3 = xb[(nc * 4 + 3) * DIM + d];
            #pragma unroll
            for (int i = 0; i < 4; ++i) {
                float4 pv = *reinterpret_cast<const float4*>(&P[rg * 4 + i][nc * 4]);
                acc[i] = fmaf(pv.x, xv0, acc[i]);
                acc[i] = fmaf(pv.y, xv1, acc[i]);
                acc[i] = fmaf(pv.z, xv2, acc[i]);
                acc[i] = fmaf(pv.w, xv3, acc[i]);
            }
        }
        #pragma unroll
        for (int i = 0; i < 4; ++i)
            cbuf[(size_t)(b * SEQ + m0 + rg * 4 + i) * DIM + d] = acc[i];
        __threadfence();
        __syncthreads();
        if (tid == 0) atomicAdd(&f2[b * 2 + (m0 >> 6)], 1u);

    } else {
        // ================= k3 producer: bf16 MFMA GEMM =================
        const int kb = bid - 400;
        unsigned short (*As)[72] = (unsigned short(*)[72])smem;
        unsigned short (*Bs)[72] = (unsigned short(*)[72])(smem + 9216);
        const int lane = tid & 63;
        const int w    = tid >> 6;
        const int l15  = lane & 15;
        const int g4   = lane >> 4;
        const int wm   = w >> 2;
        const int wn   = w & 3;
        const int mt   = kb & 31;
        const int m0   = mt * 64;
        const int n0   = (kb >> 5) * 192;

        if (tid == 0) {
            while (atomicAdd(&f2[(m0 >> 7) * 2 + ((m0 >> 6) & 1)], 0u) < 8u)
                __builtin_amdgcn_s_sleep(2);
        }
        __syncthreads();
        __threadfence();

        floatx4 Cf[2][3];
        #pragma unroll
        for (int i = 0; i < 2; ++i)
            #pragma unroll
            for (int j = 0; j < 3; ++j) Cf[i][j] = (floatx4){0.f, 0.f, 0.f, 0.f};

        for (int ch = 0; ch < 8; ++ch) {
            const int kbase = ch * 64;
            #pragma unroll
            for (int q = 0; q < 2; ++q) {
                int fi = q * 512 + tid;
                int row = fi >> 4, kq = (fi & 15) << 2;
                int kg = kbase + kq;
                const float* src = (kg < 256) ? &x[(size_t)(m0 + row) * DIM + kg]
                                              : &cbuf[(size_t)(m0 + row) * DIM + (kg - 256)];
                float4 v = *reinterpret_cast<const float4*>(src);
                unsigned short* dst = &As[row][kq];
                dst[0] = bf16bits(v.x); dst[1] = bf16bits(v.y);
                dst[2] = bf16bits(v.z); dst[3] = bf16bits(v.w);
            }
            #pragma unroll
            for (int q = 0; q < 6; ++q) {
                int fi = q * 512 + tid;
                int krow = fi / 48, nq = (fi % 48) << 2;
                float4 v = *reinterpret_cast<const float4*>(
                    &gk[(size_t)(kbase + krow) * K3H + n0 + nq]);
                Bs[nq + 0][krow] = bf16bits(v.x);
                Bs[nq + 1][krow] = bf16bits(v.y);
                Bs[nq + 2][krow] = bf16bits(v.z);
                Bs[nq + 3][krow] = bf16bits(v.w);
            }
            __syncthreads();
            #pragma unroll
            for (int kk = 0; kk < 2; ++kk) {
                short8 af[2], bf[3];
                #pragma unroll
                for (int i = 0; i < 2; ++i)
                    af[i] = *reinterpret_cast<const short8*>(&As[wm * 32 + i * 16 + l15][kk * 32 + g4 * 8]);
                #pragma unroll
                for (int j = 0; j < 3; ++j)
                    bf[j] = *reinterpret_cast<const short8*>(&Bs[wn * 48 + j * 16 + l15][kk * 32 + g4 * 8]);
                #pragma unroll
                for (int i = 0; i < 2; ++i)
                    #pragma unroll
                    for (int j = 0; j < 3; ++j)
                        Cf[i][j] = __builtin_amdgcn_mfma_f32_16x16x32_bf16(af[i], bf[j], Cf[i][j], 0, 0, 0);
            }
            __syncthreads();
        }

        #pragma unroll
        for (int j = 0; j < 3; ++j) {
            const int nbase = n0 + wn * 48 + j * 16;
            const int col = nbase + l15;
            const float sc = (nbase >= 512) ? LOG2E2 : LOG2E;
            const float bv = ((col < 512) ? (gb[col] + gb[K3H + col]) : gb[col]) * sc;
            #pragma unroll
            for (int i = 0; i < 2; ++i) {
                const int rbase = m0 + wm * 32 + i * 16 + g4 * 4;
                #pragma unroll
                for (int r = 0; r < 4; ++r)
                    xp[(size_t)(rbase + r) * K3H + col] = fmaf(Cf[i][j][r], sc, bv);
            }
        }
        __threadfence();
        __syncthreads();
        if (tid == 0) atomicAdd(&f3[mt], 1u);
    }
}

extern "C" void kernel_launch(void* const* d_in, const int* in_sizes, int n_in,
                              void* d_out, int out_size, void* d_ws, size_t ws_size,
                              hipStream_t stream) {
    const float* feat = (const float*)d_in[0];
    const float* w1   = (const float*)d_in[1];
    const float* w2   = (const float*)d_in[2];
    const float* bias = (const float*)d_in[3];
    const float* v3   = (const float*)d_in[4];
    const float* gk   = (const float*)d_in[5];
    const float* grk  = (const float*)d_in[6];
    const float* gb   = (const float*)d_in[7];
    float* out = (float*)d_out;

    char* wsb = (char*)d_ws;
    float* left  = (float*)(wsb);
    float* right = (float*)(wsb + (size_t)2 * 1024 * 1024);
    float* cbuf  = (float*)(wsb + (size_t)4 * 1024 * 1024);
    float* xp    = (float*)(wsb + (size_t)6 * 1024 * 1024);
    unsigned* flags = (unsigned*)(wsb + (size_t)12 * 1024 * 1024);

    hipMemsetAsync(flags, 0, 512, stream);
    k_fused<<<528, 512, 0, stream>>>(feat, w1, w2, bias, v3, gk, grk, gb,
                                     left, right, cbuf, xp, out, flags);
}

// Round 17
// 237.882 us; speedup vs baseline: 1.6697x; 1.6697x over previous
//
#include <hip/hip_runtime.h>
#include <hip/hip_bf16.h>

typedef __attribute__((ext_vector_type(8))) short short8;
typedef __attribute__((ext_vector_type(4))) float floatx4;

#define NSEQ 16
#define SEQ 128
#define DIM 256
#define HID 256
#define K3H 768
#define K2D 512
#define LOG2E 1.442695041f
#define LOG2E2 2.885390082f
#define WS_STRIDE 772   // 768 + 4: breaks 16-way preload bank conflict to 2-way (free)

__device__ __forceinline__ float frcp(float x) { return __builtin_amdgcn_rcpf(x); }
__device__ __forceinline__ unsigned short bf16bits(float v) {
    unsigned u = __builtin_bit_cast(unsigned, v);
    unsigned r = (u + 0x7FFFu + ((u >> 16) & 1u)) >> 16;
    return (unsigned short)r;
}
// async global->LDS DMA, 16B/lane: LDS dest = uniform base + lane*16 (HW rule)
__device__ __forceinline__ void load_lds16(const float* gsrc, float* ldsbase) {
    __builtin_amdgcn_global_load_lds(
        (const __attribute__((address_space(1))) void*)gsrc,
        (__attribute__((address_space(3))) void*)ldsbase, 16, 0, 0);
}

// ---------------- K1: left = x@w1, right = x@w2  (8 rows/block, round-12 proven) ----------------
// outputs prescaled by 2*log2e (k2 consumes via exp2-tanh)
__global__ __launch_bounds__(256) void k1_leftright(
        const float* __restrict__ x, const float* __restrict__ w1,
        const float* __restrict__ w2, float* __restrict__ left,
        float* __restrict__ right) {
    __shared__ __align__(16) float xs[8][DIM];
    const int tid = threadIdx.x;
    const int r0 = blockIdx.x * 8;
    #pragma unroll
    for (int i = 0; i < 8; ++i) xs[i][tid] = x[(r0 + i) * DIM + tid];
    __syncthreads();
    float accL[8], accR[8];
    #pragma unroll
    for (int i = 0; i < 8; ++i) { accL[i] = 0.f; accR[i] = 0.f; }
    #pragma unroll 4
    for (int d = 0; d < DIM; ++d) {
        float wa = w1[d * DIM + tid];
        float wb = w2[d * DIM + tid];
        #pragma unroll
        for (int i = 0; i < 8; ++i) {
            float xv = xs[i][d];
            accL[i] = fmaf(xv, wa, accL[i]);
            accR[i] = fmaf(xv, wb, accR[i]);
        }
    }
    #pragma unroll
    for (int i = 0; i < 8; ++i) {
        left[(r0 + i) * DIM + tid]  = accL[i] * LOG2E2;
        right[(r0 + i) * DIM + tid] = accR[i] * LOG2E2;
    }
}

// ---------------- K2 v3: 4 m-rows per block, 512 blocks (2/CU), register softmax ----------------
__global__ __launch_bounds__(256) void k2_attn(
        const float* __restrict__ x, const float* __restrict__ left,
        const float* __restrict__ right, const float* __restrict__ bias,
        const float* __restrict__ v3, float* __restrict__ cout) {
    __shared__ __align__(16) float lm[4][DIM];
    __shared__ __align__(16) float v3s[DIM];
    __shared__ __align__(16) float P[4][SEQ];
    const int tid = threadIdx.x;
    const int b  = blockIdx.x >> 5;          // sequence
    const int m0 = (blockIdx.x & 31) * 4;    // first of 4 m-rows

    v3s[tid] = v3[tid];
    #pragma unroll
    for (int i = 0; i < 4; ++i)
        lm[i][tid] = left[(size_t)(b * SEQ + m0 + i) * DIM + tid] + bias[tid] * LOG2E2;
    __syncthreads();

    // ---- scores: wave mi owns row m0+mi; lane nl covers n = nl, nl+64 ----
    const int mi = tid >> 6;        // 0..3 (wave)
    const int nl = tid & 63;        // lane
    float s0 = 0.f, s1 = 0.f;
    const float4* lv4 = reinterpret_cast<const float4*>(lm[mi]);
    const float4* vv4 = reinterpret_cast<const float4*>(v3s);
    const float4* r0v = reinterpret_cast<const float4*>(right + (size_t)(b * SEQ + nl) * DIM);
    const float4* r1v = reinterpret_cast<const float4*>(right + (size_t)(b * SEQ + nl + 64) * DIM);
    #pragma unroll 2
    for (int d4 = 0; d4 < DIM / 4; ++d4) {
        float4 lv = lv4[d4];
        float4 vv = vv4[d4];
        float4 ra = r0v[d4];
        float4 rb = r1v[d4];
        float a0 = 1.f - 2.f * frcp(1.f + __builtin_amdgcn_exp2f(lv.x + ra.x));
        float a1 = 1.f - 2.f * frcp(1.f + __builtin_amdgcn_exp2f(lv.y + ra.y));
        float a2 = 1.f - 2.f * frcp(1.f + __builtin_amdgcn_exp2f(lv.z + ra.z));
        float a3 = 1.f - 2.f * frcp(1.f + __builtin_amdgcn_exp2f(lv.w + ra.w));
        s0 = fmaf(a0, vv.x, s0); s0 = fmaf(a1, vv.y, s0);
        s0 = fmaf(a2, vv.z, s0); s0 = fmaf(a3, vv.w, s0);
        float b0 = 1.f - 2.f * frcp(1.f + __builtin_amdgcn_exp2f(lv.x + rb.x));
        float b1 = 1.f - 2.f * frcp(1.f + __builtin_amdgcn_exp2f(lv.y + rb.y));
        float b2 = 1.f - 2.f * frcp(1.f + __builtin_amdgcn_exp2f(lv.z + rb.z));
        float b3 = 1.f - 2.f * frcp(1.f + __builtin_amdgcn_exp2f(lv.w + rb.w));
        s1 = fmaf(b0, vv.x, s1); s1 = fmaf(b1, vv.y, s1);
        s1 = fmaf(b2, vv.z, s1); s1 = fmaf(b3, vv.w, s1);
    }
    // ---- softmax in registers (wave-wide shuffle reduce) ----
    float mx = fmaxf(s0, s1);
    #pragma unroll
    for (int off = 32; off >= 1; off >>= 1) mx = fmaxf(mx, __shfl_xor(mx, off, 64));
    float e0 = __expf(s0 - mx), e1 = __expf(s1 - mx);
    float sm = e0 + e1;
    #pragma unroll
    for (int off = 32; off >= 1; off >>= 1) sm += __shfl_xor(sm, off, 64);
    float inv = frcp(sm);
    P[mi][nl]      = e0 * inv;
    P[mi][nl + 64] = e1 * inv;
    __syncthreads();

    // ---- c[m0+i][d] = sum_n P[i][n] x[b,n,d]; thread = d ----
    float acc[4] = {0.f, 0.f, 0.f, 0.f};
    const float* xb = x + (size_t)b * SEQ * DIM;
    for (int nc = 0; nc < SEQ / 4; ++nc) {
        float xv0 = xb[(nc * 4 + 0) * DIM + tid];
        float xv1 = xb[(nc * 4 + 1) * DIM + tid];
        float xv2 = xb[(nc * 4 + 2) * DIM + tid];
        float xv3 = xb[(nc * 4 + 3) * DIM + tid];
        #pragma unroll
        for (int i = 0; i < 4; ++i) {
            float4 pv = *reinterpret_cast<const float4*>(&P[i][nc * 4]);
            acc[i] = fmaf(pv.x, xv0, acc[i]);
            acc[i] = fmaf(pv.y, xv1, acc[i]);
            acc[i] = fmaf(pv.z, xv2, acc[i]);
            acc[i] = fmaf(pv.w, xv3, acc[i]);
        }
    }
    #pragma unroll
    for (int i = 0; i < 4; ++i)
        cout[(size_t)(b * SEQ + m0 + i) * DIM + tid] = acc[i];
}

// ---------------- K3 v2: bf16 MFMA GEMM (round-10 proven) ----------------
__global__ __launch_bounds__(512) void k3_mfma(
        const float* __restrict__ x, const float* __restrict__ c,
        const float* __restrict__ gk, const float* __restrict__ gbias,
        float* __restrict__ xp) {
    __shared__ __align__(16) unsigned short As[64][72];    // [m][k]
    __shared__ __align__(16) unsigned short Bs[192][72];   // [n][k] (transposed)
    const int tid  = threadIdx.x;
    const int lane = tid & 63;
    const int w    = tid >> 6;
    const int l15  = lane & 15;
    const int g4   = lane >> 4;
    const int wm   = w >> 2;          // 0..1
    const int wn   = w & 3;           // 0..3
    const int m0   = (blockIdx.x & 31) * 64;
    const int n0   = (blockIdx.x >> 5) * 192;

    floatx4 Cf[2][3];
    #pragma unroll
    for (int i = 0; i < 2; ++i)
        #pragma unroll
        for (int j = 0; j < 3; ++j) Cf[i][j] = (floatx4){0.f, 0.f, 0.f, 0.f};

    for (int ch = 0; ch < 8; ++ch) {
        const int kbase = ch * 64;
        #pragma unroll
        for (int q = 0; q < 2; ++q) {
            int fi = q * 512 + tid;
            int row = fi >> 4, kq = (fi & 15) << 2;
            int kg = kbase + kq;
            const float* src = (kg < 256) ? &x[(size_t)(m0 + row) * DIM + kg]
                                          : &c[(size_t)(m0 + row) * DIM + (kg - 256)];
            float4 v = *reinterpret_cast<const float4*>(src);
            unsigned short* dst = &As[row][kq];
            dst[0] = bf16bits(v.x); dst[1] = bf16bits(v.y);
            dst[2] = bf16bits(v.z); dst[3] = bf16bits(v.w);
        }
        #pragma unroll
        for (int q = 0; q < 6; ++q) {
            int fi = q * 512 + tid;
            int krow = fi / 48, nq = (fi % 48) << 2;
            float4 v = *reinterpret_cast<const float4*>(
                &gk[(size_t)(kbase + krow) * K3H + n0 + nq]);
            Bs[nq + 0][krow] = bf16bits(v.x);
            Bs[nq + 1][krow] = bf16bits(v.y);
            Bs[nq + 2][krow] = bf16bits(v.z);
            Bs[nq + 3][krow] = bf16bits(v.w);
        }
        __syncthreads();
        #pragma unroll
        for (int kk = 0; kk < 2; ++kk) {
            short8 af[2], bf[3];
            #pragma unroll
            for (int i = 0; i < 2; ++i)
                af[i] = *reinterpret_cast<const short8*>(&As[wm * 32 + i * 16 + l15][kk * 32 + g4 * 8]);
            #pragma unroll
            for (int j = 0; j < 3; ++j)
                bf[j] = *reinterpret_cast<const short8*>(&Bs[wn * 48 + j * 16 + l15][kk * 32 + g4 * 8]);
            #pragma unroll
            for (int i = 0; i < 2; ++i)
                #pragma unroll
                for (int j = 0; j < 3; ++j)
                    Cf[i][j] = __builtin_amdgcn_mfma_f32_16x16x32_bf16(af[i], bf[j], Cf[i][j], 0, 0, 0);
        }
        __syncthreads();
    }

    #pragma unroll
    for (int j = 0; j < 3; ++j) {
        const int nbase = n0 + wn * 48 + j * 16;
        const int col = nbase + l15;
        const float sc = (nbase >= 512) ? LOG2E2 : LOG2E;
        const float bv = ((col < 512) ? (gbias[col] + gbias[K3H + col]) : gbias[col]) * sc;
        #pragma unroll
        for (int i = 0; i < 2; ++i) {
            const int rbase = m0 + wm * 32 + i * 16 + g4 * 4;
            #pragma unroll
            for (int r = 0; r < 4; ++r)
                xp[(size_t)(rbase + r) * K3H + col] = fmaf(Cf[i][j][r], sc, bv);
        }
    }
}

// ---------------- K4 v11 (round-12 champion, 181us): staged preload + unroll-2 step ----------------
__global__ __launch_bounds__(512) void k4_gru(
        const float* __restrict__ rec, const float* __restrict__ gbias,
        const float* __restrict__ xp, float* __restrict__ out) {
    __shared__ __align__(16) float ws[16 * WS_STRIDE];    // 49.4KB preload staging
    __shared__ __align__(16) float xq0[K3H], xq1[K3H], xq2[K3H];
    __shared__ __align__(16) unsigned short hbf[2][HID];  // 1KB dbuf h (bf16)
    const int tid  = threadIdx.x;
    const int lane = tid & 63;
    const int wv   = tid >> 6;     // 0..7
    const int seq  = blockIdx.x;   // 0..15
    const int l15  = lane & 15;
    const int g4   = lane >> 4;    // 0..3

    // ---- Preload rec_kernel as prescaled bf16 B-fragments (staged, proven) ----
    short8 Bf[6][8];
    #pragma unroll
    for (int part = 0; part < 16; ++part) {
        #pragma unroll
        for (int q = 0; q < 6; ++q) {
            int fi = q * 512 + tid;
            int row = fi / 192, c4 = fi % 192;
            reinterpret_cast<float4*>(ws)[row * (WS_STRIDE / 4) + c4] =
                reinterpret_cast<const float4*>(rec + part * 16 * K3H)[fi];
        }
        __syncthreads();
        const int kc = part >> 1, half = part & 1;
        #pragma unroll
        for (int u = 0; u < 6; ++u) {
            const float sc = (u >= 4) ? LOG2E2 : LOG2E;
            const int col = (u >> 1) * 256 + (u & 1) * 16 + wv * 32 + l15;
            #pragma unroll
            for (int j = 0; j < 8; ++j) {
                int r = g4 * 8 + j;
                if ((r >> 4) == half)
                    Bf[u][kc][j] = (short)bf16bits(ws[(r & 15) * WS_STRIDE + col] * sc);
            }
        }
        __syncthreads();
    }

    const int dd = wv * 32 + (lane & 31);
    const float brh_l = gbias[K3H + 512 + dd] * LOG2E2;
    const int tsel = (lane >> 4) & 1;

    const float* xps = xp + (size_t)seq * SEQ * K3H;
    float* outs = out + (size_t)seq * SEQ * HID;

    float h = 0.f;
    if (tid < HID) hbf[0][tid] = 0;

    // prologue: DMA rows 0 and 1; full drain once
    if (wv < 3) {
        load_lds16(xps + wv * 256 + (lane << 2),       xq0 + wv * 256);
        load_lds16(xps + K3H + wv * 256 + (lane << 2), xq1 + wv * 256);
    }
    asm volatile("s_waitcnt vmcnt(0)" ::: "memory");
    __syncthreads();

    // rotating xq pointers: p0 = read(s), p1 = read(s+1), p2 = DMA target (s+2)
    float* p0 = xq0;
    float* p1 = xq1;
    float* p2 = xq2;

    // one GRU step; CB/NB are compile-time via unroll-2
    #define K4_STEP(s_, CB, NB)                                                         \
    {                                                                                   \
        const int sp = ((s_) + 2 < SEQ) ? (s_) + 2 : SEQ - 1;                           \
        if (wv < 3)                                                                     \
            load_lds16(xps + (size_t)sp * K3H + wv * 256 + (lane << 2), p2 + wv * 256); \
        short8 av[8];                                                                   \
        _Pragma("unroll")                                                               \
        for (int kc = 0; kc < 8; ++kc)                                                  \
            av[kc] = *reinterpret_cast<const short8*>(&hbf[CB][kc * 32 + g4 * 8]);      \
        const float xz = p0[dd];                                                        \
        const float xr = p0[256 + dd];                                                  \
        const float xh = p0[512 + dd];                                                  \
        floatx4 C[6];                                                                   \
        _Pragma("unroll")                                                               \
        for (int u = 0; u < 6; ++u) C[u] = (floatx4){0.f, 0.f, 0.f, 0.f};               \
        _Pragma("unroll")                                                               \
        for (int kc = 0; kc < 8; ++kc) {                                                \
            _Pragma("unroll")                                                           \
            for (int u = 0; u < 6; ++u)                                                 \
                C[u] = __builtin_amdgcn_mfma_f32_16x16x32_bf16(av[kc], Bf[u][kc],       \
                                                               C[u], 0, 0, 0);         \
        }                                                                               \
        if (lane < 32) {                                                                \
            float rz = tsel ? C[1][0] : C[0][0];                                        \
            float rr = tsel ? C[3][0] : C[2][0];                                        \
            float rh = tsel ? C[5][0] : C[4][0];                                        \
            float z  = frcp(1.f + __builtin_amdgcn_exp2f(-(rz + xz)));                  \
            float r  = frcp(1.f + __builtin_amdgcn_exp2f(-(rr + xr)));                  \
            float th = fmaf(r, rh + brh_l, xh);                                         \
            float hh = 1.f - 2.f * frcp(1.f + __builtin_amdgcn_exp2f(th));              \
            h = hh + z * (h - hh);                                                      \
            hbf[NB][dd] = bf16bits(h);                                                  \
            outs[(s_) * HID + dd] = h;                                                  \
        }                                                                               \
        asm volatile("s_waitcnt vmcnt(3) lgkmcnt(0)\n\ts_barrier" ::: "memory");        \
        float* tmp_ = p0; p0 = p1; p1 = p2; p2 = tmp_;                                  \
    }

    for (int s = 0; s < SEQ; s += 2) {
        K4_STEP(s,     0, 1)
        K4_STEP(s + 1, 1, 0)
    }
    #undef K4_STEP
}

extern "C" void kernel_launch(void* const* d_in, const int* in_sizes, int n_in,
                              void* d_out, int out_size, void* d_ws, size_t ws_size,
                              hipStream_t stream) {
    const float* feat = (const float*)d_in[0];
    const float* w1   = (const float*)d_in[1];
    const float* w2   = (const float*)d_in[2];
    const float* bias = (const float*)d_in[3];
    const float* v3   = (const float*)d_in[4];
    const float* gk   = (const float*)d_in[5];
    const float* grk  = (const float*)d_in[6];
    const float* gb   = (const float*)d_in[7];
    float* out = (float*)d_out;

    char* wsb = (char*)d_ws;
    float* left  = (float*)(wsb);
    float* right = (float*)(wsb + (size_t)2 * 1024 * 1024);
    float* cbuf  = (float*)(wsb + (size_t)4 * 1024 * 1024);
    float* xp    = (float*)(wsb + (size_t)6 * 1024 * 1024);

    k1_leftright<<<2048 / 8, 256, 0, stream>>>(feat, w1, w2, left, right);
    k2_attn<<<NSEQ * 32, 256, 0, stream>>>(feat, left, right, bias, v3, cbuf);
    k3_mfma<<<128, 512, 0, stream>>>(feat, cbuf, gk, gb, xp);
    k4_gru<<<NSEQ, 512, 0, stream>>>(grk, gb, xp, out);
}